// Round 7
// baseline (271.889 us; speedup 1.0000x reference)
//
#include <hip/hip_runtime.h>
#include <hip/hip_bf16.h>

typedef __attribute__((ext_vector_type(8))) short s16x8;
typedef __attribute__((ext_vector_type(4))) float f32x4;

#define GLOAD_LDS16(gsrc, ldst) \
  __builtin_amdgcn_global_load_lds((const __attribute__((address_space(1))) void*)(gsrc), \
      (__attribute__((address_space(3))) void*)(ldst), 16, 0, 0)

// ---------------------------------------------------------------------------
// f32 -> bf16 convert
// ---------------------------------------------------------------------------
__global__ __launch_bounds__(256) void cvt_bf16(const float* __restrict__ in,
                                                __hip_bfloat16* __restrict__ out, long n) {
  long i = ((long)blockIdx.x * 256 + threadIdx.x) * 4;
  if (i + 3 >= n) return;
  float4 v = *(const float4*)(in + i);
  __hip_bfloat16 tmp[4] = {__float2bfloat16(v.x), __float2bfloat16(v.y),
                           __float2bfloat16(v.z), __float2bfloat16(v.w)};
  *(ushort4*)((unsigned short*)out + i) = *(const ushort4*)tmp;
}

// ---------------------------------------------------------------------------
// merge + transpose:  Out[b][n][k] = bf16( W[k][n] + sum_e coeff[b][e]*T[e][k][n] )
// ---------------------------------------------------------------------------
template<int NB>
__global__ __launch_bounds__(256) void merge_transpose(
    const float* __restrict__ Wb, const float* __restrict__ T,
    const float* __restrict__ coeff, __hip_bfloat16* __restrict__ Out,
    int K, int N, int nE) {
  int ntn = N >> 6;
  int k0 = (blockIdx.x / ntn) << 6;
  int n0 = (blockIdx.x % ntn) << 6;
  int t = threadIdx.x;
  long KN = (long)K * N;

  float4 accb[NB][4];
#pragma unroll
  for (int i = 0; i < 4; ++i) {
    int e = i * 256 + t; int kk = e >> 4, nn = (e & 15) << 2;
    float4 bv = *(const float4*)&Wb[(long)(k0 + kk) * N + n0 + nn];
#pragma unroll
    for (int b2 = 0; b2 < NB; ++b2) accb[b2][i] = bv;
  }
  for (int ex = 0; ex < nE; ++ex) {
    float c[NB];
#pragma unroll
    for (int b2 = 0; b2 < NB; ++b2) c[b2] = coeff[b2 * 8 + ex];
#pragma unroll
    for (int i = 0; i < 4; ++i) {
      int e = i * 256 + t; int kk = e >> 4, nn = (e & 15) << 2;
      float4 tv = *(const float4*)&T[(long)ex * KN + (long)(k0 + kk) * N + n0 + nn];
#pragma unroll
      for (int b2 = 0; b2 < NB; ++b2) {
        accb[b2][i].x += c[b2] * tv.x; accb[b2][i].y += c[b2] * tv.y;
        accb[b2][i].z += c[b2] * tv.z; accb[b2][i].w += c[b2] * tv.w;
      }
    }
  }
  __shared__ __hip_bfloat16 lds[64 * 66];
  for (int b2 = 0; b2 < NB; ++b2) {
    __syncthreads();
#pragma unroll
    for (int i = 0; i < 4; ++i) {
      int e = i * 256 + t; int kk = e >> 4, nn = (e & 15) << 2;
      lds[kk * 66 + nn + 0] = __float2bfloat16(accb[b2][i].x);
      lds[kk * 66 + nn + 1] = __float2bfloat16(accb[b2][i].y);
      lds[kk * 66 + nn + 2] = __float2bfloat16(accb[b2][i].z);
      lds[kk * 66 + nn + 3] = __float2bfloat16(accb[b2][i].w);
    }
    __syncthreads();
#pragma unroll
    for (int i = 0; i < 4; ++i) {
      int o = i * 256 + t; int n2 = o >> 4, k2 = (o & 15) << 2;
      __hip_bfloat16 tmp[4];
#pragma unroll
      for (int j = 0; j < 4; ++j) tmp[j] = lds[(k2 + j) * 66 + n2];
      *(ushort4*)((unsigned short*)&Out[(long)b2 * KN + (long)(n0 + n2) * K + k0 + k2]) =
          *(const ushort4*)tmp;
    }
  }
}

// ---------------------------------------------------------------------------
// merged bias: out[b][i] = base[i] + sum_e coeff[b][e]*T[e][i]
// ---------------------------------------------------------------------------
__global__ __launch_bounds__(256) void merge_bias(const float* __restrict__ base,
                                                  const float* __restrict__ T,
                                                  const float* __restrict__ coeff,
                                                  float* __restrict__ out, int n) {
  int b = blockIdx.y;
  int i = blockIdx.x * 256 + threadIdx.x;
  if (i >= n) return;
  float v = base[i];
#pragma unroll
  for (int e = 0; e < 8; ++e) v += coeff[b * 8 + e] * T[(long)e * n + i];
  out[(long)b * n + i] = v;
}

// ---------------------------------------------------------------------------
// 128x128 GEMM, 4 waves, single-buffer 2-barrier loop (r1/r6 structure).
// Packed swapped-MFMA epilogue.  XCD decode (heuristic xcd = blockIdx.x % 8):
//   MODE 0 (router, grid (256,1)): XCD pins 4 A m-panels, sweeps 8 B n-panels.
//   MODE 2 (L2-layer, grid 512): xcd = b, m-fastest, kc (K-split) outermost.
// ---------------------------------------------------------------------------
template<int MODE, int ACT, bool OUTBF>
__global__ __launch_bounds__(256, 2) void gemm_bt(
    const __hip_bfloat16* __restrict__ A, const __hip_bfloat16* __restrict__ BT,
    const float* __restrict__ bias, void* __restrict__ Out,
    int N, int K, long sA, long sB, long sBias, long sOut,
    int kLen, long ksOut) {
  int bid = blockIdx.x;
  int b, m, n, kc = 0;
  if (MODE == 0)      { b = blockIdx.y; m = (bid & 7) * 4 + ((bid >> 3) & 3); n = bid >> 5; }
  else                { b = bid & 7; int tile = bid >> 3; m = tile & 3; n = (tile >> 2) & 7; kc = tile >> 5; }
  int m0 = m << 7, n0 = n << 7;
  int kOff = kc * kLen;

  const __hip_bfloat16* Ab = A + (long)b * sA;
  const __hip_bfloat16* Bb = BT + (long)b * sB;

  __shared__ __align__(16) __hip_bfloat16 As[128 * 64];
  __shared__ __align__(16) __hip_bfloat16 Bs[128 * 64];

  int t = threadIdx.x;
  int lane = t & 63;
  int wid = t >> 6;
  int wm = wid >> 1, wn = wid & 1;
  int lr = lane & 15, kg = lane >> 4;

  f32x4 acc[4][4] = {};

  for (int kt = kOff; kt < kOff + kLen; kt += 64) {
#pragma unroll
    for (int is = 0; is < 4; ++is) {
      int ci = is * 256 + t;
      int row = ci >> 3, cpos = ci & 7;
      int csrc = cpos ^ (row & 7);
      GLOAD_LDS16(Ab + (long)(m0 + row) * K + kt + csrc * 8, &As[ci * 8]);
      GLOAD_LDS16(Bb + (long)(n0 + row) * K + kt + csrc * 8, &Bs[ci * 8]);
    }
    __syncthreads();
#pragma unroll
    for (int ks = 0; ks < 2; ++ks) {
      s16x8 af[4], bfr[4];
#pragma unroll
      for (int mi = 0; mi < 4; ++mi) {
        int row = wm * 64 + mi * 16 + lr;
        int c = (ks * 4 + kg) ^ (row & 7);
        af[mi] = *(const s16x8*)&As[row * 64 + c * 8];
      }
#pragma unroll
      for (int ni = 0; ni < 4; ++ni) {
        int row = wn * 64 + ni * 16 + lr;
        int c = (ks * 4 + kg) ^ (row & 7);
        bfr[ni] = *(const s16x8*)&Bs[row * 64 + c * 8];
      }
#pragma unroll
      for (int mi = 0; mi < 4; ++mi)
#pragma unroll
        for (int ni = 0; ni < 4; ++ni)
          acc[mi][ni] = __builtin_amdgcn_mfma_f32_16x16x32_bf16(bfr[ni], af[mi], acc[mi][ni], 0, 0, 0);
    }
    __syncthreads();
  }

#pragma unroll
  for (int mi = 0; mi < 4; ++mi) {
    int row = m0 + wm * 64 + mi * 16 + lr;
#pragma unroll
    for (int ni = 0; ni < 4; ++ni) {
      int colb = n0 + wn * 64 + ni * 16 + kg * 4;
      float bv4[4] = {0.f, 0.f, 0.f, 0.f};
      if (bias != nullptr) {
        float4 bb = *(const float4*)&bias[(long)b * sBias + colb];
        bv4[0] = bb.x; bv4[1] = bb.y; bv4[2] = bb.z; bv4[3] = bb.w;
      }
      float v[4];
#pragma unroll
      for (int j = 0; j < 4; ++j) {
        v[j] = acc[mi][ni][j] + bv4[j];
        if (ACT == 1) v[j] = fmaxf(v[j], 0.f);
        else if (ACT == 2) v[j] = 0.5f * v[j] * (1.f + erff(v[j] * 0.70710678118f));
      }
      long off = kc * ksOut + (long)b * sOut + (long)row * N + colb;
      if (OUTBF) {
        __hip_bfloat16 tmp[4] = {__float2bfloat16(v[0]), __float2bfloat16(v[1]),
                                 __float2bfloat16(v[2]), __float2bfloat16(v[3])};
        *(ushort4*)((unsigned short*)Out + off) = *(const ushort4*)tmp;
      } else {
        *(float4*)((float*)Out + off) = make_float4(v[0], v[1], v[2], v[3]);
      }
    }
  }
}

// ---------------------------------------------------------------------------
// L1 FFN GEMM: 256x256 tile, 8 waves, dbuf + prefetch + counted vmcnt(8)
// (r4-verified loop), xcd=b m-fastest decode.  Halves staged bytes vs 128^2:
// per sample 2m x 16n blocks, B duplicated 2x (was 4x), A 16x (was 32x).
// A = xb[b] [512,1024], BT = Wb[b] [4096,1024], out hmid[b] gelu bf16.
// grid = 256 blocks (1/CU), 512 threads.
// ---------------------------------------------------------------------------
__global__ __launch_bounds__(512, 2) void gemm256_l1(
    const __hip_bfloat16* __restrict__ A, const __hip_bfloat16* __restrict__ BT,
    const float* __restrict__ bias, __hip_bfloat16* __restrict__ Out) {
  int bid = blockIdx.x;
  int b = bid & 7;
  int tile = bid >> 3;          // 0..31
  int m0 = (tile & 1) << 8;     // 2 m-blocks of 256 (m-fastest: pairs share B)
  int n0 = (tile >> 1) << 8;    // 16 n-blocks of 256
  const int K = 1024, N = 4096;

  const __hip_bfloat16* Ab = A + (long)b * 512 * 1024;
  const __hip_bfloat16* Bb = BT + (long)b * 4096 * 1024;
  const float* biasb = bias + (long)b * 4096;

  __shared__ __align__(16) __hip_bfloat16 As[2][256 * 64];
  __shared__ __align__(16) __hip_bfloat16 Bs[2][256 * 64];

  int t = threadIdx.x;
  int lane = t & 63;
  int wid = t >> 6;          // 0..7
  int wm = wid >> 2;         // 0..1 -> 128-row half
  int wn = wid & 3;          // 0..3 -> 64-col quarter
  int lr = lane & 15, kg = lane >> 4;

  f32x4 acc[8][4] = {};

  auto stage = [&](int buf, int kt) {
#pragma unroll
    for (int is = 0; is < 4; ++is) {
      int ci = is * 512 + t;
      int row = ci >> 3, cpos = ci & 7;
      int csrc = cpos ^ (row & 7);
      GLOAD_LDS16(Ab + (long)(m0 + row) * K + kt + csrc * 8, &As[buf][ci * 8]);
    }
#pragma unroll
    for (int is = 0; is < 4; ++is) {
      int ci = is * 512 + t;
      int row = ci >> 3, cpos = ci & 7;
      int csrc = cpos ^ (row & 7);
      GLOAD_LDS16(Bb + (long)(n0 + row) * K + kt + csrc * 8, &Bs[buf][ci * 8]);
    }
  };

  auto compute = [&](int buf) {
#pragma unroll
    for (int ks = 0; ks < 2; ++ks) {
      s16x8 af[8], bfr[4];
#pragma unroll
      for (int mi = 0; mi < 8; ++mi) {
        int row = wm * 128 + mi * 16 + lr;
        int c = (ks * 4 + kg) ^ (row & 7);
        af[mi] = *(const s16x8*)&As[buf][row * 64 + c * 8];
      }
#pragma unroll
      for (int ni = 0; ni < 4; ++ni) {
        int row = wn * 64 + ni * 16 + lr;
        int c = (ks * 4 + kg) ^ (row & 7);
        bfr[ni] = *(const s16x8*)&Bs[buf][row * 64 + c * 8];
      }
#pragma unroll
      for (int mi = 0; mi < 8; ++mi)
#pragma unroll
        for (int ni = 0; ni < 4; ++ni)
          acc[mi][ni] = __builtin_amdgcn_mfma_f32_16x16x32_bf16(bfr[ni], af[mi], acc[mi][ni], 0, 0, 0);
    }
  };

  const int nk = 16;
  stage(0, 0);
  for (int it = 0; it < nk; ++it) {
    if (it + 1 < nk) {
      stage((it + 1) & 1, (it + 1) << 6);
      asm volatile("s_waitcnt vmcnt(8)" ::: "memory");   // prev-tile loads done
    } else {
      asm volatile("s_waitcnt vmcnt(0)" ::: "memory");
    }
    asm volatile("s_barrier" ::: "memory");
    compute(it & 1);
    asm volatile("s_barrier" ::: "memory");              // reads done before re-stage
  }

#pragma unroll
  for (int mi = 0; mi < 8; ++mi) {
    int row = m0 + wm * 128 + mi * 16 + lr;
#pragma unroll
    for (int ni = 0; ni < 4; ++ni) {
      int colb = n0 + wn * 64 + ni * 16 + kg * 4;
      float4 bb = *(const float4*)&biasb[colb];
      float v[4] = {acc[mi][ni][0] + bb.x, acc[mi][ni][1] + bb.y,
                    acc[mi][ni][2] + bb.z, acc[mi][ni][3] + bb.w};
#pragma unroll
      for (int j = 0; j < 4; ++j)
        v[j] = 0.5f * v[j] * (1.f + erff(v[j] * 0.70710678118f));
      long off = (long)b * 512 * 4096 + (long)row * N + colb;
      __hip_bfloat16 tmp[4] = {__float2bfloat16(v[0]), __float2bfloat16(v[1]),
                               __float2bfloat16(v[2]), __float2bfloat16(v[3])};
      *(ushort4*)((unsigned short*)Out + off) = *(const ushort4*)tmp;
    }
  }
}

// ---------------------------------------------------------------------------
// K-split reduce: out[i] = f32(p[i]) + f32(p[i+ksOut]) + b2b[b][d]
// ---------------------------------------------------------------------------
__global__ __launch_bounds__(256) void reduce2_bias(
    const __hip_bfloat16* __restrict__ p, const float* __restrict__ b2b,
    float* __restrict__ out, long ksOut) {
  long i = ((long)blockIdx.x * 256 + threadIdx.x) * 8;
  const unsigned short* ps = (const unsigned short*)p;
  ushort4 a0 = *(const ushort4*)(ps + i);
  ushort4 a1 = *(const ushort4*)(ps + i + 4);
  ushort4 c0 = *(const ushort4*)(ps + ksOut + i);
  ushort4 c1 = *(const ushort4*)(ps + ksOut + i + 4);
  int d = (int)(i & 1023);
  int b = (int)(i >> 19);
  const float* bp = b2b + (long)b * 1024 + d;
  float o[8];
  unsigned short av[8] = {a0.x, a0.y, a0.z, a0.w, a1.x, a1.y, a1.z, a1.w};
  unsigned short cv[8] = {c0.x, c0.y, c0.z, c0.w, c1.x, c1.y, c1.z, c1.w};
#pragma unroll
  for (int j = 0; j < 8; ++j) {
    __hip_bfloat16 ab = *(__hip_bfloat16*)&av[j], cb = *(__hip_bfloat16*)&cv[j];
    o[j] = __bfloat162float(ab) + __bfloat162float(cb) + bp[j];
  }
  *(float4*)(out + i) = make_float4(o[0], o[1], o[2], o[3]);
  *(float4*)(out + i + 4) = make_float4(o[4], o[5], o[6], o[7]);
}

// ---------------------------------------------------------------------------
// router logits + per-row softmax
// ---------------------------------------------------------------------------
__global__ __launch_bounds__(256) void router_logits(
    const __hip_bfloat16* __restrict__ Hg2, const float* __restrict__ Wgo,
    const float* __restrict__ bgo, float* __restrict__ probs) {
  int r = blockIdx.x;
  int t = threadIdx.x;
  float acc[8] = {};
#pragma unroll
  for (int j = 0; j < 4; ++j) {
    int k = j * 256 + t;
    float h = __bfloat162float(Hg2[(long)r * 1024 + k]);
    const float4* wp = (const float4*)&Wgo[k * 8];
    float4 w0 = wp[0], w1 = wp[1];
    acc[0] += h * w0.x; acc[1] += h * w0.y; acc[2] += h * w0.z; acc[3] += h * w0.w;
    acc[4] += h * w1.x; acc[5] += h * w1.y; acc[6] += h * w1.z; acc[7] += h * w1.w;
  }
#pragma unroll
  for (int off = 32; off >= 1; off >>= 1)
#pragma unroll
    for (int e = 0; e < 8; ++e) acc[e] += __shfl_down(acc[e], off);
  __shared__ float lds[4][8];
  int wid = t >> 6, lane = t & 63;
  if (lane == 0)
#pragma unroll
    for (int e = 0; e < 8; ++e) lds[wid][e] = acc[e];
  __syncthreads();
  if (t == 0) {
    float lg[8];
#pragma unroll
    for (int e = 0; e < 8; ++e) lg[e] = lds[0][e] + lds[1][e] + lds[2][e] + lds[3][e] + bgo[e];
    float mx = lg[0];
#pragma unroll
    for (int e = 1; e < 8; ++e) mx = fmaxf(mx, lg[e]);
    float s = 0.f;
#pragma unroll
    for (int e = 0; e < 8; ++e) { lg[e] = __expf(lg[e] - mx); s += lg[e]; }
    float inv = 1.f / s;
#pragma unroll
    for (int e = 0; e < 8; ++e) probs[(long)r * 8 + e] = lg[e] * inv;
  }
}

// ---------------------------------------------------------------------------
__global__ __launch_bounds__(256) void router_mean(
    const float* __restrict__ probs, const float* __restrict__ ohe,
    float* __restrict__ gate_out, float* __restrict__ coeff) {
  int b = blockIdx.x;
  int t = threadIdx.x;
  int e = t & 7, sg = t >> 3;
  float s = 0.f;
#pragma unroll
  for (int j = 0; j < 16; ++j)
    s += probs[((long)b * 512 + sg + j * 32) * 8 + e];
  __shared__ float lds[256];
  lds[t] = s;
  __syncthreads();
  if (t < 8) {
    float tot = 0.f;
#pragma unroll
    for (int g = 0; g < 32; ++g) tot += lds[g * 8 + t];
    float gw = tot / 512.f;
    gate_out[b * 8 + t] = gw;
    coeff[b * 8 + t] = gw + ohe[b * 8 + t];
  }
}

// ---------------------------------------------------------------------------
extern "C" void kernel_launch(void* const* d_in, const int* in_sizes, int n_in,
                              void* d_out, int out_size, void* d_ws, size_t ws_size,
                              hipStream_t stream) {
  const float* x    = (const float*)d_in[0];
  const float* ohe  = (const float*)d_in[1];
  const float* W1   = (const float*)d_in[2];
  const float* b1   = (const float*)d_in[3];
  const float* W2   = (const float*)d_in[4];
  const float* b2   = (const float*)d_in[5];
  const float* T_W1 = (const float*)d_in[6];
  const float* T_b1 = (const float*)d_in[7];
  const float* T_W2 = (const float*)d_in[8];
  const float* T_b2 = (const float*)d_in[9];
  const float* Wg1  = (const float*)d_in[10];
  const float* bg1  = (const float*)d_in[11];
  const float* Wg2  = (const float*)d_in[12];
  const float* bg2  = (const float*)d_in[13];
  const float* Wgo  = (const float*)d_in[14];
  const float* bgo  = (const float*)d_in[15];
  float* out = (float*)d_out;                 // [8,512,1024] then gate [8,8]
  float* gate_out = out + (long)8 * 512 * 1024;

  char* w = (char*)d_ws;
  __hip_bfloat16* xb   = (__hip_bfloat16*)(w);             // 8 MB (reused as L2 partials)
  __hip_bfloat16* Wg1T = (__hip_bfloat16*)(w + 8388608);
  __hip_bfloat16* Wg2T = (__hip_bfloat16*)(w + 10485760);
  __hip_bfloat16* Hg1  = (__hip_bfloat16*)(w + 12582912);
  __hip_bfloat16* Hg2  = (__hip_bfloat16*)(w + 20971520);
  float*          probs= (float*)(w + 29360128);
  float*          coeff= (float*)(w + 29491200);
  float*          b1b  = (float*)(w + 29492224);
  float*          b2b  = (float*)(w + 29623296);
  __hip_bfloat16* hmid = (__hip_bfloat16*)(w + 29656064);  // 33.5 MB
  __hip_bfloat16* Wb   = (__hip_bfloat16*)(w + 63210496);  // 67 MB, W1bT then W2bT
  __hip_bfloat16* part = (__hip_bfloat16*)(w);             // L2 partials: 2 x 8 MB (xb dead)

  const long SSD = (long)512 * 1024;
  const long SSF = (long)512 * 4096;

  // 1. x -> bf16
  cvt_bf16<<<4096, 256, 0, stream>>>(x, xb, (long)8 * 512 * 1024);
  // 2. router weight transpose-converts
  merge_transpose<1><<<16 * 16, 256, 0, stream>>>(Wg1, nullptr, nullptr, Wg1T, 1024, 1024, 0);
  merge_transpose<1><<<16 * 16, 256, 0, stream>>>(Wg2, nullptr, nullptr, Wg2T, 1024, 1024, 0);
  // 3. router GEMMs (M=4096 flat, N=1024, K=1024), relu
  gemm_bt<0, 1, true><<<dim3(256, 1), 256, 0, stream>>>(xb, Wg1T, bg1, Hg1,
      1024, 1024, 0, 0, 0, 0, 1024, 0);
  gemm_bt<0, 1, true><<<dim3(256, 1), 256, 0, stream>>>(Hg1, Wg2T, bg2, Hg2,
      1024, 1024, 0, 0, 0, 0, 1024, 0);
  // 4. logits + softmax, then mean + coeff
  router_logits<<<4096, 256, 0, stream>>>(Hg2, Wgo, bgo, probs);
  router_mean<<<8, 256, 0, stream>>>(probs, ohe, gate_out, coeff);
  // 5. merged biases
  merge_bias<<<dim3(16, 8), 256, 0, stream>>>(b1, T_b1, coeff, b1b, 4096);
  merge_bias<<<dim3(4, 8), 256, 0, stream>>>(b2, T_b2, coeff, b2b, 1024);
  // 6. W1bT (K=1024, N=4096), then layer-1 GEMM: 256^2 dbuf counted-vmcnt,
  //    xcd=b m-fastest (halved staged bytes: 268 MB vs 524 MB)
  merge_transpose<8><<<16 * 64, 256, 0, stream>>>(W1, T_W1, coeff, Wb, 1024, 4096, 8);
  gemm256_l1<<<dim3(256, 1), 512, 0, stream>>>(xb, Wb, b1b, hmid);
  // 7. W2bT (K=4096, N=1024), then layer-2 GEMM (r6 form: 128^2, xcd=b,
  //    K-split x2, bf16 partials), then reduce + bias -> d_out
  merge_transpose<8><<<64 * 16, 256, 0, stream>>>(W2, T_W2, coeff, Wb, 4096, 1024, 8);
  gemm_bt<2, 0, true><<<dim3(512, 1), 256, 0, stream>>>(hmid, Wb, nullptr, part,
      1024, 4096, SSF, (long)4096 * 1024, 0, SSD, 2048, (long)8 * 512 * 1024);
  reduce2_bias<<<2048, 256, 0, stream>>>(part, b2b, out, (long)8 * 512 * 1024);
}

// Round 8
// 258.554 us; speedup vs baseline: 1.0516x; 1.0516x over previous
//
#include <hip/hip_runtime.h>
#include <hip/hip_bf16.h>

typedef __attribute__((ext_vector_type(8))) short s16x8;
typedef __attribute__((ext_vector_type(4))) float f32x4;

#define GLOAD_LDS16(gsrc, ldst) \
  __builtin_amdgcn_global_load_lds((const __attribute__((address_space(1))) void*)(gsrc), \
      (__attribute__((address_space(3))) void*)(ldst), 16, 0, 0)

// ---------------------------------------------------------------------------
// f32 -> bf16 convert
// ---------------------------------------------------------------------------
__global__ __launch_bounds__(256) void cvt_bf16(const float* __restrict__ in,
                                                __hip_bfloat16* __restrict__ out, long n) {
  long i = ((long)blockIdx.x * 256 + threadIdx.x) * 4;
  if (i + 3 >= n) return;
  float4 v = *(const float4*)(in + i);
  __hip_bfloat16 tmp[4] = {__float2bfloat16(v.x), __float2bfloat16(v.y),
                           __float2bfloat16(v.z), __float2bfloat16(v.w)};
  *(ushort4*)((unsigned short*)out + i) = *(const ushort4*)tmp;
}

// ---------------------------------------------------------------------------
// merge + transpose:  Out[b][n][k] = bf16( W[k][n] + sum_e coeff[b][e]*T[e][k][n] )
// ---------------------------------------------------------------------------
template<int NB>
__global__ __launch_bounds__(256) void merge_transpose(
    const float* __restrict__ Wb, const float* __restrict__ T,
    const float* __restrict__ coeff, __hip_bfloat16* __restrict__ Out,
    int K, int N, int nE) {
  int ntn = N >> 6;
  int k0 = (blockIdx.x / ntn) << 6;
  int n0 = (blockIdx.x % ntn) << 6;
  int t = threadIdx.x;
  long KN = (long)K * N;

  float4 accb[NB][4];
#pragma unroll
  for (int i = 0; i < 4; ++i) {
    int e = i * 256 + t; int kk = e >> 4, nn = (e & 15) << 2;
    float4 bv = *(const float4*)&Wb[(long)(k0 + kk) * N + n0 + nn];
#pragma unroll
    for (int b2 = 0; b2 < NB; ++b2) accb[b2][i] = bv;
  }
  for (int ex = 0; ex < nE; ++ex) {
    float c[NB];
#pragma unroll
    for (int b2 = 0; b2 < NB; ++b2) c[b2] = coeff[b2 * 8 + ex];
#pragma unroll
    for (int i = 0; i < 4; ++i) {
      int e = i * 256 + t; int kk = e >> 4, nn = (e & 15) << 2;
      float4 tv = *(const float4*)&T[(long)ex * KN + (long)(k0 + kk) * N + n0 + nn];
#pragma unroll
      for (int b2 = 0; b2 < NB; ++b2) {
        accb[b2][i].x += c[b2] * tv.x; accb[b2][i].y += c[b2] * tv.y;
        accb[b2][i].z += c[b2] * tv.z; accb[b2][i].w += c[b2] * tv.w;
      }
    }
  }
  __shared__ __hip_bfloat16 lds[64 * 66];
  for (int b2 = 0; b2 < NB; ++b2) {
    __syncthreads();
#pragma unroll
    for (int i = 0; i < 4; ++i) {
      int e = i * 256 + t; int kk = e >> 4, nn = (e & 15) << 2;
      lds[kk * 66 + nn + 0] = __float2bfloat16(accb[b2][i].x);
      lds[kk * 66 + nn + 1] = __float2bfloat16(accb[b2][i].y);
      lds[kk * 66 + nn + 2] = __float2bfloat16(accb[b2][i].z);
      lds[kk * 66 + nn + 3] = __float2bfloat16(accb[b2][i].w);
    }
    __syncthreads();
#pragma unroll
    for (int i = 0; i < 4; ++i) {
      int o = i * 256 + t; int n2 = o >> 4, k2 = (o & 15) << 2;
      __hip_bfloat16 tmp[4];
#pragma unroll
      for (int j = 0; j < 4; ++j) tmp[j] = lds[(k2 + j) * 66 + n2];
      *(ushort4*)((unsigned short*)&Out[(long)b2 * KN + (long)(n0 + n2) * K + k0 + k2]) =
          *(const ushort4*)tmp;
    }
  }
}

// ---------------------------------------------------------------------------
// merged bias: out[b][i] = base[i] + sum_e coeff[b][e]*T[e][i]
// ---------------------------------------------------------------------------
__global__ __launch_bounds__(256) void merge_bias(const float* __restrict__ base,
                                                  const float* __restrict__ T,
                                                  const float* __restrict__ coeff,
                                                  float* __restrict__ out, int n) {
  int b = blockIdx.y;
  int i = blockIdx.x * 256 + threadIdx.x;
  if (i >= n) return;
  float v = base[i];
#pragma unroll
  for (int e = 0; e < 8; ++e) v += coeff[b * 8 + e] * T[(long)e * n + i];
  out[(long)b * n + i] = v;
}

// ---------------------------------------------------------------------------
// 128x128 GEMM, 4 waves, single-buffer 2-barrier loop.  Packed swapped-MFMA
// epilogue.  MODE 0: routers.  MODE 2: L2-layer (xcd=b, K-split x2).
// ---------------------------------------------------------------------------
template<int MODE, int ACT, bool OUTBF>
__global__ __launch_bounds__(256, 2) void gemm_bt(
    const __hip_bfloat16* __restrict__ A, const __hip_bfloat16* __restrict__ BT,
    const float* __restrict__ bias, void* __restrict__ Out,
    int N, int K, long sA, long sB, long sBias, long sOut,
    int kLen, long ksOut) {
  int bid = blockIdx.x;
  int b, m, n, kc = 0;
  if (MODE == 0)      { b = blockIdx.y; m = (bid & 7) * 4 + ((bid >> 3) & 3); n = bid >> 5; }
  else                { b = bid & 7; int tile = bid >> 3; m = tile & 3; n = (tile >> 2) & 7; kc = tile >> 5; }
  int m0 = m << 7, n0 = n << 7;
  int kOff = kc * kLen;

  const __hip_bfloat16* Ab = A + (long)b * sA;
  const __hip_bfloat16* Bb = BT + (long)b * sB;

  __shared__ __align__(16) __hip_bfloat16 As[128 * 64];
  __shared__ __align__(16) __hip_bfloat16 Bs[128 * 64];

  int t = threadIdx.x;
  int lane = t & 63;
  int wid = t >> 6;
  int wm = wid >> 1, wn = wid & 1;
  int lr = lane & 15, kg = lane >> 4;

  f32x4 acc[4][4] = {};

  for (int kt = kOff; kt < kOff + kLen; kt += 64) {
#pragma unroll
    for (int is = 0; is < 4; ++is) {
      int ci = is * 256 + t;
      int row = ci >> 3, cpos = ci & 7;
      int csrc = cpos ^ (row & 7);
      GLOAD_LDS16(Ab + (long)(m0 + row) * K + kt + csrc * 8, &As[ci * 8]);
      GLOAD_LDS16(Bb + (long)(n0 + row) * K + kt + csrc * 8, &Bs[ci * 8]);
    }
    __syncthreads();
#pragma unroll
    for (int ks = 0; ks < 2; ++ks) {
      s16x8 af[4], bfr[4];
#pragma unroll
      for (int mi = 0; mi < 4; ++mi) {
        int row = wm * 64 + mi * 16 + lr;
        int c = (ks * 4 + kg) ^ (row & 7);
        af[mi] = *(const s16x8*)&As[row * 64 + c * 8];
      }
#pragma unroll
      for (int ni = 0; ni < 4; ++ni) {
        int row = wn * 64 + ni * 16 + lr;
        int c = (ks * 4 + kg) ^ (row & 7);
        bfr[ni] = *(const s16x8*)&Bs[row * 64 + c * 8];
      }
#pragma unroll
      for (int mi = 0; mi < 4; ++mi)
#pragma unroll
        for (int ni = 0; ni < 4; ++ni)
          acc[mi][ni] = __builtin_amdgcn_mfma_f32_16x16x32_bf16(bfr[ni], af[mi], acc[mi][ni], 0, 0, 0);
    }
    __syncthreads();
  }

#pragma unroll
  for (int mi = 0; mi < 4; ++mi) {
    int row = m0 + wm * 64 + mi * 16 + lr;
#pragma unroll
    for (int ni = 0; ni < 4; ++ni) {
      int colb = n0 + wn * 64 + ni * 16 + kg * 4;
      float bv4[4] = {0.f, 0.f, 0.f, 0.f};
      if (bias != nullptr) {
        float4 bb = *(const float4*)&bias[(long)b * sBias + colb];
        bv4[0] = bb.x; bv4[1] = bb.y; bv4[2] = bb.z; bv4[3] = bb.w;
      }
      float v[4];
#pragma unroll
      for (int j = 0; j < 4; ++j) {
        v[j] = acc[mi][ni][j] + bv4[j];
        if (ACT == 1) v[j] = fmaxf(v[j], 0.f);
        else if (ACT == 2) v[j] = 0.5f * v[j] * (1.f + erff(v[j] * 0.70710678118f));
      }
      long off = kc * ksOut + (long)b * sOut + (long)row * N + colb;
      if (OUTBF) {
        __hip_bfloat16 tmp[4] = {__float2bfloat16(v[0]), __float2bfloat16(v[1]),
                                 __float2bfloat16(v[2]), __float2bfloat16(v[3])};
        *(ushort4*)((unsigned short*)Out + off) = *(const ushort4*)tmp;
      } else {
        *(float4*)((float*)Out + off) = make_float4(v[0], v[1], v[2], v[3]);
      }
    }
  }
}

// ---------------------------------------------------------------------------
// L1 FFN GEMM: 128(M) x 256(N) tile, 8 waves, SINGLE-buffer syncthreads loop
// (r6-proven structure), 48 KB LDS -> 2 blocks/CU (launch_bounds caps VGPR).
// Staged bytes: B duplicated 2x (vs 4x at 128^2) -> 384 MB total.
// xcd=b decode, m-fastest (4 m-blocks share each B n-panel within an XCD).
// A = xb[b] [512,1024], BT = Wb[b] [4096,1024], out hmid[b] gelu bf16.
// grid = 512 blocks, 512 threads.
// ---------------------------------------------------------------------------
__global__ __launch_bounds__(512, 4) void gemm_l1(
    const __hip_bfloat16* __restrict__ A, const __hip_bfloat16* __restrict__ BT,
    const float* __restrict__ bias, __hip_bfloat16* __restrict__ Out) {
  const int K = 1024, N = 4096;
  int bid = blockIdx.x;
  int b = bid & 7;
  int tile = bid >> 3;          // 0..63
  int m0 = (tile & 3) << 7;     // 4 m-blocks of 128, m-fastest
  int n0 = (tile >> 2) << 8;    // 16 n-blocks of 256

  const __hip_bfloat16* Ab = A + (long)b * 512 * 1024;
  const __hip_bfloat16* Bb = BT + (long)b * 4096 * 1024;
  const float* biasb = bias + (long)b * 4096;

  __shared__ __align__(16) __hip_bfloat16 As[128 * 64];
  __shared__ __align__(16) __hip_bfloat16 Bs[256 * 64];

  int t = threadIdx.x;
  int lane = t & 63;
  int wid = t >> 6;          // 0..7
  int wm = wid >> 2;         // 0..1 -> 64-row half
  int wn = wid & 3;          // 0..3 -> 64-col quarter
  int lr = lane & 15, kg = lane >> 4;

  f32x4 acc[4][4] = {};

  for (int kt = 0; kt < K; kt += 64) {
#pragma unroll
    for (int is = 0; is < 2; ++is) {          // A: 128 rows x 8 chunks
      int ci = is * 512 + t;
      int row = ci >> 3, cpos = ci & 7;
      int csrc = cpos ^ (row & 7);
      GLOAD_LDS16(Ab + (long)(m0 + row) * K + kt + csrc * 8, &As[ci * 8]);
    }
#pragma unroll
    for (int is = 0; is < 4; ++is) {          // B: 256 rows x 8 chunks
      int ci = is * 512 + t;
      int row = ci >> 3, cpos = ci & 7;
      int csrc = cpos ^ (row & 7);
      GLOAD_LDS16(Bb + (long)(n0 + row) * K + kt + csrc * 8, &Bs[ci * 8]);
    }
    __syncthreads();
#pragma unroll
    for (int ks = 0; ks < 2; ++ks) {
      s16x8 af[4], bfr[4];
#pragma unroll
      for (int mi = 0; mi < 4; ++mi) {
        int row = wm * 64 + mi * 16 + lr;
        int c = (ks * 4 + kg) ^ (row & 7);
        af[mi] = *(const s16x8*)&As[row * 64 + c * 8];
      }
#pragma unroll
      for (int ni = 0; ni < 4; ++ni) {
        int row = wn * 64 + ni * 16 + lr;
        int c = (ks * 4 + kg) ^ (row & 7);
        bfr[ni] = *(const s16x8*)&Bs[row * 64 + c * 8];
      }
#pragma unroll
      for (int mi = 0; mi < 4; ++mi)
#pragma unroll
        for (int ni = 0; ni < 4; ++ni)
          acc[mi][ni] = __builtin_amdgcn_mfma_f32_16x16x32_bf16(bfr[ni], af[mi], acc[mi][ni], 0, 0, 0);
    }
    __syncthreads();
  }

#pragma unroll
  for (int mi = 0; mi < 4; ++mi) {
    int row = m0 + wm * 64 + mi * 16 + lr;
#pragma unroll
    for (int ni = 0; ni < 4; ++ni) {
      int colb = n0 + wn * 64 + ni * 16 + kg * 4;
      float4 bb = *(const float4*)&biasb[colb];
      float v[4] = {acc[mi][ni][0] + bb.x, acc[mi][ni][1] + bb.y,
                    acc[mi][ni][2] + bb.z, acc[mi][ni][3] + bb.w};
#pragma unroll
      for (int j = 0; j < 4; ++j)
        v[j] = 0.5f * v[j] * (1.f + erff(v[j] * 0.70710678118f));
      long off = (long)b * 512 * 4096 + (long)row * N + colb;
      __hip_bfloat16 tmp[4] = {__float2bfloat16(v[0]), __float2bfloat16(v[1]),
                               __float2bfloat16(v[2]), __float2bfloat16(v[3])};
      *(ushort4*)((unsigned short*)Out + off) = *(const ushort4*)tmp;
    }
  }
}

// ---------------------------------------------------------------------------
// K-split reduce: out[i] = f32(p[i]) + f32(p[i+ksOut]) + b2b[b][d]
// ---------------------------------------------------------------------------
__global__ __launch_bounds__(256) void reduce2_bias(
    const __hip_bfloat16* __restrict__ p, const float* __restrict__ b2b,
    float* __restrict__ out, long ksOut) {
  long i = ((long)blockIdx.x * 256 + threadIdx.x) * 8;
  const unsigned short* ps = (const unsigned short*)p;
  ushort4 a0 = *(const ushort4*)(ps + i);
  ushort4 a1 = *(const ushort4*)(ps + i + 4);
  ushort4 c0 = *(const ushort4*)(ps + ksOut + i);
  ushort4 c1 = *(const ushort4*)(ps + ksOut + i + 4);
  int d = (int)(i & 1023);
  int b = (int)(i >> 19);
  const float* bp = b2b + (long)b * 1024 + d;
  float o[8];
  unsigned short av[8] = {a0.x, a0.y, a0.z, a0.w, a1.x, a1.y, a1.z, a1.w};
  unsigned short cv[8] = {c0.x, c0.y, c0.z, c0.w, c1.x, c1.y, c1.z, c1.w};
#pragma unroll
  for (int j = 0; j < 8; ++j) {
    __hip_bfloat16 ab = *(__hip_bfloat16*)&av[j], cb = *(__hip_bfloat16*)&cv[j];
    o[j] = __bfloat162float(ab) + __bfloat162float(cb) + bp[j];
  }
  *(float4*)(out + i) = make_float4(o[0], o[1], o[2], o[3]);
  *(float4*)(out + i + 4) = make_float4(o[4], o[5], o[6], o[7]);
}

// ---------------------------------------------------------------------------
// router logits + per-row softmax
// ---------------------------------------------------------------------------
__global__ __launch_bounds__(256) void router_logits(
    const __hip_bfloat16* __restrict__ Hg2, const float* __restrict__ Wgo,
    const float* __restrict__ bgo, float* __restrict__ probs) {
  int r = blockIdx.x;
  int t = threadIdx.x;
  float acc[8] = {};
#pragma unroll
  for (int j = 0; j < 4; ++j) {
    int k = j * 256 + t;
    float h = __bfloat162float(Hg2[(long)r * 1024 + k]);
    const float4* wp = (const float4*)&Wgo[k * 8];
    float4 w0 = wp[0], w1 = wp[1];
    acc[0] += h * w0.x; acc[1] += h * w0.y; acc[2] += h * w0.z; acc[3] += h * w0.w;
    acc[4] += h * w1.x; acc[5] += h * w1.y; acc[6] += h * w1.z; acc[7] += h * w1.w;
  }
#pragma unroll
  for (int off = 32; off >= 1; off >>= 1)
#pragma unroll
    for (int e = 0; e < 8; ++e) acc[e] += __shfl_down(acc[e], off);
  __shared__ float lds[4][8];
  int wid = t >> 6, lane = t & 63;
  if (lane == 0)
#pragma unroll
    for (int e = 0; e < 8; ++e) lds[wid][e] = acc[e];
  __syncthreads();
  if (t == 0) {
    float lg[8];
#pragma unroll
    for (int e = 0; e < 8; ++e) lg[e] = lds[0][e] + lds[1][e] + lds[2][e] + lds[3][e] + bgo[e];
    float mx = lg[0];
#pragma unroll
    for (int e = 1; e < 8; ++e) mx = fmaxf(mx, lg[e]);
    float s = 0.f;
#pragma unroll
    for (int e = 0; e < 8; ++e) { lg[e] = __expf(lg[e] - mx); s += lg[e]; }
    float inv = 1.f / s;
#pragma unroll
    for (int e = 0; e < 8; ++e) probs[(long)r * 8 + e] = lg[e] * inv;
  }
}

// ---------------------------------------------------------------------------
__global__ __launch_bounds__(256) void router_mean(
    const float* __restrict__ probs, const float* __restrict__ ohe,
    float* __restrict__ gate_out, float* __restrict__ coeff) {
  int b = blockIdx.x;
  int t = threadIdx.x;
  int e = t & 7, sg = t >> 3;
  float s = 0.f;
#pragma unroll
  for (int j = 0; j < 16; ++j)
    s += probs[((long)b * 512 + sg + j * 32) * 8 + e];
  __shared__ float lds[256];
  lds[t] = s;
  __syncthreads();
  if (t < 8) {
    float tot = 0.f;
#pragma unroll
    for (int g = 0; g < 32; ++g) tot += lds[g * 8 + t];
    float gw = tot / 512.f;
    gate_out[b * 8 + t] = gw;
    coeff[b * 8 + t] = gw + ohe[b * 8 + t];
  }
}

// ---------------------------------------------------------------------------
extern "C" void kernel_launch(void* const* d_in, const int* in_sizes, int n_in,
                              void* d_out, int out_size, void* d_ws, size_t ws_size,
                              hipStream_t stream) {
  const float* x    = (const float*)d_in[0];
  const float* ohe  = (const float*)d_in[1];
  const float* W1   = (const float*)d_in[2];
  const float* b1   = (const float*)d_in[3];
  const float* W2   = (const float*)d_in[4];
  const float* b2   = (const float*)d_in[5];
  const float* T_W1 = (const float*)d_in[6];
  const float* T_b1 = (const float*)d_in[7];
  const float* T_W2 = (const float*)d_in[8];
  const float* T_b2 = (const float*)d_in[9];
  const float* Wg1  = (const float*)d_in[10];
  const float* bg1  = (const float*)d_in[11];
  const float* Wg2  = (const float*)d_in[12];
  const float* bg2  = (const float*)d_in[13];
  const float* Wgo  = (const float*)d_in[14];
  const float* bgo  = (const float*)d_in[15];
  float* out = (float*)d_out;                 // [8,512,1024] then gate [8,8]
  float* gate_out = out + (long)8 * 512 * 1024;

  char* w = (char*)d_ws;
  __hip_bfloat16* xb   = (__hip_bfloat16*)(w);             // 8 MB (reused as L2 partials)
  __hip_bfloat16* Wg1T = (__hip_bfloat16*)(w + 8388608);
  __hip_bfloat16* Wg2T = (__hip_bfloat16*)(w + 10485760);
  __hip_bfloat16* Hg1  = (__hip_bfloat16*)(w + 12582912);
  __hip_bfloat16* Hg2  = (__hip_bfloat16*)(w + 20971520);
  float*          probs= (float*)(w + 29360128);
  float*          coeff= (float*)(w + 29491200);
  float*          b1b  = (float*)(w + 29492224);
  float*          b2b  = (float*)(w + 29623296);
  __hip_bfloat16* hmid = (__hip_bfloat16*)(w + 29656064);  // 33.5 MB
  __hip_bfloat16* Wb   = (__hip_bfloat16*)(w + 63210496);  // 67 MB, W1bT then W2bT
  __hip_bfloat16* part = (__hip_bfloat16*)(w);             // L2 partials: 2 x 8 MB (xb dead)

  const long SSD = (long)512 * 1024;
  const long SSF = (long)512 * 4096;

  // 1. x -> bf16
  cvt_bf16<<<4096, 256, 0, stream>>>(x, xb, (long)8 * 512 * 1024);
  // 2. router weight transpose-converts
  merge_transpose<1><<<16 * 16, 256, 0, stream>>>(Wg1, nullptr, nullptr, Wg1T, 1024, 1024, 0);
  merge_transpose<1><<<16 * 16, 256, 0, stream>>>(Wg2, nullptr, nullptr, Wg2T, 1024, 1024, 0);
  // 3. router GEMMs (M=4096 flat, N=1024, K=1024), relu
  gemm_bt<0, 1, true><<<dim3(256, 1), 256, 0, stream>>>(xb, Wg1T, bg1, Hg1,
      1024, 1024, 0, 0, 0, 0, 1024, 0);
  gemm_bt<0, 1, true><<<dim3(256, 1), 256, 0, stream>>>(Hg1, Wg2T, bg2, Hg2,
      1024, 1024, 0, 0, 0, 0, 1024, 0);
  // 4. logits + softmax, then mean + coeff
  router_logits<<<4096, 256, 0, stream>>>(Hg2, Wgo, bgo, probs);
  router_mean<<<8, 256, 0, stream>>>(probs, ohe, gate_out, coeff);
  // 5. merged biases
  merge_bias<<<dim3(16, 8), 256, 0, stream>>>(b1, T_b1, coeff, b1b, 4096);
  merge_bias<<<dim3(4, 8), 256, 0, stream>>>(b2, T_b2, coeff, b2b, 1024);
  // 6. W1bT (K=1024, N=4096), then layer-1 GEMM: 128x256 8-wave single-buffer,
  //    xcd=b m-fastest (staged 384 MB vs 524, occupancy 2 blocks/CU)
  merge_transpose<8><<<16 * 64, 256, 0, stream>>>(W1, T_W1, coeff, Wb, 1024, 4096, 8);
  gemm_l1<<<dim3(512, 1), 512, 0, stream>>>(xb, Wb, b1b, hmid);
  // 7. W2bT (K=4096, N=1024), then layer-2 GEMM (r6 form: 128^2, xcd=b,
  //    K-split x2, bf16 partials), then reduce + bias -> d_out
  merge_transpose<8><<<64 * 16, 256, 0, stream>>>(W2, T_W2, coeff, Wb, 4096, 1024, 8);
  gemm_bt<2, 0, true><<<dim3(512, 1), 256, 0, stream>>>(hmid, Wb, nullptr, part,
      1024, 4096, SSF, (long)4096 * 1024, 0, SSD, 2048, (long)8 * 512 * 1024);
  reduce2_bias<<<2048, 256, 0, stream>>>(part, b2b, out, (long)8 * 512 * 1024);
}